// Round 10
// baseline (491.714 us; speedup 1.0000x reference)
//
#include <hip/hip_runtime.h>
#include <stdint.h>

#define D    128
#define ED   5
#define BLK  512
#define WPB  8
#define W1S  296   // u16 stride; word-stride 148 -> conflict-free b128 reads
#define W2S  136
#define HS   136
#define US   264
#define GRID 256

typedef __attribute__((ext_vector_type(8))) short bf16x8;
typedef __attribute__((ext_vector_type(4))) float f32x4;

__device__ __forceinline__ unsigned short f2bf(float f) {
    union { float f; uint32_t u; } c; c.f = f;
    uint32_t r = (c.u + 0x7fffu + ((c.u >> 16) & 1u)) >> 16;
    return (unsigned short)r;
}
__device__ __forceinline__ float bflo(uint32_t u) {
    union { uint32_t u; float f; } c; c.u = u << 16; return c.f;
}
__device__ __forceinline__ float bfhi(uint32_t u) {
    union { uint32_t u; float f; } c; c.u = u & 0xffff0000u; return c.f;
}
__device__ __forceinline__ bf16x8 cvt8(const float* __restrict__ p) {
    float4 a = *(const float4*)p;
    float4 b = *(const float4*)(p + 4);
    bf16x8 r;
    r[0] = (short)f2bf(a.x); r[1] = (short)f2bf(a.y);
    r[2] = (short)f2bf(a.z); r[3] = (short)f2bf(a.w);
    r[4] = (short)f2bf(b.x); r[5] = (short)f2bf(b.y);
    r[6] = (short)f2bf(b.z); r[7] = (short)f2bf(b.w);
    return r;
}
__device__ __forceinline__ bool detect64(const int* ei) {
    return (ei[1] == 0) & (ei[3] == 0) & (ei[5] == 0) &
           (ei[7] == 0) & (ei[9] == 0) & (ei[11] == 0);
}

// ---- fused: bf16-convert x AND histogram dst counts ----
__global__ __launch_bounds__(512)
void cvt_count_kernel(const float* __restrict__ in, unsigned short* __restrict__ out,
                      int n8, const int* __restrict__ ei, int* __restrict__ cnt, int E) {
    const int i = blockIdx.x * 512 + threadIdx.x;
    if (i < n8) {
        float4 a = ((const float4*)in)[2 * i];
        float4 b = ((const float4*)in)[2 * i + 1];
        union { unsigned short s[8]; uint4 v; } p;
        p.s[0] = f2bf(a.x); p.s[1] = f2bf(a.y); p.s[2] = f2bf(a.z); p.s[3] = f2bf(a.w);
        p.s[4] = f2bf(b.x); p.s[5] = f2bf(b.y); p.s[6] = f2bf(b.z); p.s[7] = f2bf(b.w);
        ((uint4*)out)[i] = p.v;
    } else {
        const int e = i - n8;
        if (e < E) {
            const bool is64 = detect64(ei);
            int d = is64 ? ei[2 * ((size_t)E + e)] : ei[(size_t)E + e];
            atomicAdd(&cnt[d], 1);
        }
    }
}

// ---------------- CSR build (parallel scan) ----------------
__global__ __launch_bounds__(1024)
void scan_blk_kernel(const int* __restrict__ cnt, int* __restrict__ part,
                     int* __restrict__ bsum, int N) {
    __shared__ int wsum[16];
    const int tid = threadIdx.x, wave = tid >> 6, lane = tid & 63;
    const int idx = blockIdx.x * 1024 + tid;
    int v = (idx < N) ? cnt[idx] : 0;
    int s = v;
    #pragma unroll
    for (int off = 1; off < 64; off <<= 1) {
        int t = __shfl_up(s, off, 64);
        if (lane >= off) s += t;
    }
    if (lane == 63) wsum[wave] = s;
    __syncthreads();
    if (wave == 0 && lane < 16) {
        int ws_ = wsum[lane];
        #pragma unroll
        for (int off = 1; off < 16; off <<= 1) {
            int t = __shfl_up(ws_, off, 64);
            if (lane >= off) ws_ += t;
        }
        wsum[lane] = ws_;
    }
    __syncthreads();
    const int excl = ((wave == 0) ? 0 : wsum[wave - 1]) + (s - v);
    if (idx < N) part[idx] = excl;
    if (tid == 0) bsum[blockIdx.x] = wsum[15];
}

__global__ __launch_bounds__(1024)
void scan_top_kernel(int* __restrict__ bsum, int nb) {
    __shared__ int wsum[16];
    const int tid = threadIdx.x, wave = tid >> 6, lane = tid & 63;
    int v = (tid < nb) ? bsum[tid] : 0;
    int s = v;
    #pragma unroll
    for (int off = 1; off < 64; off <<= 1) {
        int t = __shfl_up(s, off, 64);
        if (lane >= off) s += t;
    }
    if (lane == 63) wsum[wave] = s;
    __syncthreads();
    if (wave == 0 && lane < 16) {
        int ws_ = wsum[lane];
        #pragma unroll
        for (int off = 1; off < 16; off <<= 1) {
            int t = __shfl_up(ws_, off, 64);
            if (lane >= off) ws_ += t;
        }
        wsum[lane] = ws_;
    }
    __syncthreads();
    const int excl = ((wave == 0) ? 0 : wsum[wave - 1]) + (s - v);
    if (tid < nb) bsum[tid] = excl;
}

__global__ __launch_bounds__(1024)
void scan_add_kernel(const int* __restrict__ part, const int* __restrict__ bsum,
                     int* __restrict__ starts, int* __restrict__ cursor,
                     int N, int E) {
    const int idx = blockIdx.x * 1024 + threadIdx.x;
    if (idx < N) {
        int v = part[idx] + bsum[blockIdx.x];
        starts[idx] = v;
        cursor[idx] = v;
    }
    if (blockIdx.x == 0 && threadIdx.x == 0) starts[N] = E;
}

// slot[e] = CSR (dst-grouped) position of edge e; coalesced write by e
__global__ __launch_bounds__(512)
void fill_kernel(const int* __restrict__ ei, int* __restrict__ cursor,
                 int* __restrict__ slotp, int E) {
    const bool is64 = detect64(ei);
    int e = blockIdx.x * 512 + threadIdx.x;
    if (e >= E) return;
    int d = is64 ? ei[2 * ((size_t)E + e)] : ei[(size_t)E + e];
    slotp[e] = atomicAdd(&cursor[d], 1);
}

// ================= EDGE MLP: M=32/wave, conflict-free transpose =================
template<bool XBF>
__global__ __launch_bounds__(BLK, 2)
void edge_mlp(const float* __restrict__ x, const unsigned short* __restrict__ xbf,
              const float* __restrict__ ea, const int* __restrict__ ei,
              const int* __restrict__ slotp,
              const float* __restrict__ w1, const float* __restrict__ b1,
              const float* __restrict__ g1, const float* __restrict__ be1,
              const float* __restrict__ w2, const float* __restrict__ b2,
              unsigned short* __restrict__ h2, int E)
{
    __shared__ unsigned short w1t[128 * W1S];
    __shared__ unsigned short w2t[128 * W2S];
    __shared__ unsigned short hb[WPB][16 * HS];

    const int tid = threadIdx.x;
    for (int i = tid; i < 288 * 128; i += BLK) {
        int k = i >> 7, n = i & 127;
        float v = (k < (2 * D + ED)) ? w1[k * 128 + n] : 0.f;
        w1t[n * W1S + k] = f2bf(v);
    }
    for (int i = tid; i < 128 * 128; i += BLK) {
        int k = i >> 7, n = i & 127;
        w2t[n * W2S + k] = f2bf(w2[k * 128 + n]);
    }
    __syncthreads();

    const bool is64 = detect64(ei);
    const int lane = tid & 63, w = tid >> 6;
    const int g = lane >> 4, c = lane & 15;

    float b1v[8], g1v[8], e1v[8], b2v[8];
    #pragma unroll
    for (int nt = 0; nt < 8; ++nt) {
        b1v[nt] = b1[nt * 16 + c];  g1v[nt] = g1[nt * 16 + c];
        e1v[nt] = be1[nt * 16 + c]; b2v[nt] = b2[nt * 16 + c];
    }

    const int nT = (E + 31) >> 5;
    const int step = gridDim.x * WPB;
    unsigned short* hw = hb[w];

    // pipeline state for the two 16-row halves
    int psl0 = 0, psl1 = 0, pe0 = 0, pe1 = 0;
    size_t pa0 = 0, pb0 = 0, pa1 = 0, pb1 = 0;
    bf16x8 pf0[9], pf1[9];

    auto loadIdx = [&](int tl) {
        const int r0 = tl * 32 + c;
        const int r1 = tl * 32 + 16 + c;
        const int rc0 = r0 < E ? r0 : E - 1;
        const int rc1 = r1 < E ? r1 : E - 1;
        pe0 = rc0; pe1 = rc1;
        int s0 = is64 ? ei[2 * (size_t)rc0]       : ei[rc0];
        int d0 = is64 ? ei[2 * ((size_t)E + rc0)] : ei[(size_t)E + rc0];
        int s1 = is64 ? ei[2 * (size_t)rc1]       : ei[rc1];
        int d1 = is64 ? ei[2 * ((size_t)E + rc1)] : ei[(size_t)E + rc1];
        pa0 = (size_t)s0 * D; pb0 = (size_t)d0 * D;
        pa1 = (size_t)s1 * D; pb1 = (size_t)d1 * D;
        psl0 = slotp[rc0]; psl1 = slotp[rc1];
    };
    auto loadFrags = [&]() {
        #pragma unroll
        for (int kk = 0; kk < 8; ++kk) {
            const size_t o0 = (kk < 4) ? pa0 + kk * 32 : pb0 + (kk - 4) * 32;
            const size_t o1 = (kk < 4) ? pa1 + kk * 32 : pb1 + (kk - 4) * 32;
            if (XBF) {
                pf0[kk] = *(const bf16x8*)(xbf + o0 + 8 * g);
                pf1[kk] = *(const bf16x8*)(xbf + o1 + 8 * g);
            } else {
                pf0[kk] = cvt8(x + o0 + 8 * g);
                pf1[kk] = cvt8(x + o1 + 8 * g);
            }
        }
        bf16x8 t0, t1;
        #pragma unroll
        for (int j = 0; j < 8; ++j) { t0[j] = 0; t1[j] = 0; }
        if (g == 0) {
            #pragma unroll
            for (int j = 0; j < ED; ++j) {
                t0[j] = (short)f2bf(ea[(size_t)pe0 * ED + j]);
                t1[j] = (short)f2bf(ea[(size_t)pe1 * ED + j]);
            }
        }
        pf0[8] = t0; pf1[8] = t1;
    };

    const f32x4 z = {0.f, 0.f, 0.f, 0.f};

    auto process = [&](f32x4* acc, int sl, int rowv) __attribute__((always_inline)) {
        float mean[4], rstd[4];
        #pragma unroll
        for (int r = 0; r < 4; ++r) {
            float s = 0.f, q = 0.f;
            #pragma unroll
            for (int nt = 0; nt < 8; ++nt) {
                float v = acc[nt][r] + b1v[nt];
                acc[nt][r] = v;
                s += v; q += v * v;
            }
            s += __shfl_xor(s, 1, 64); q += __shfl_xor(q, 1, 64);
            s += __shfl_xor(s, 2, 64); q += __shfl_xor(q, 2, 64);
            s += __shfl_xor(s, 4, 64); q += __shfl_xor(q, 4, 64);
            s += __shfl_xor(s, 8, 64); q += __shfl_xor(q, 8, 64);
            float m = s * (1.f / 128.f);
            mean[r] = m;
            rstd[r] = rsqrtf(q * (1.f / 128.f) - m * m + 1e-5f);
        }
        // paired-u32 conflict-free transpose write (even lanes write 2 cols)
        #pragma unroll
        for (int nt = 0; nt < 8; ++nt) {
            #pragma unroll
            for (int r = 0; r < 4; ++r) {
                float h = fmaxf((acc[nt][r] - mean[r]) * rstd[r] * g1v[nt] + e1v[nt], 0.f);
                float hp = __shfl_xor(h, 1, 64);
                if (!(c & 1)) {
                    uint32_t pk = (uint32_t)f2bf(h) | ((uint32_t)f2bf(hp) << 16);
                    *(uint32_t*)&hw[(4 * g + r) * HS + nt * 16 + c] = pk;
                }
            }
        }
        f32x4 acc2[8] = {z, z, z, z, z, z, z, z};
        #pragma unroll
        for (int kk = 0; kk < 4; ++kk) {
            bf16x8 hf = *(const bf16x8*)&hw[c * HS + kk * 32 + 8 * g];
            const unsigned short* wr = &w2t[c * W2S + kk * 32 + 8 * g];
            #pragma unroll
            for (int nt = 0; nt < 8; ++nt) {
                bf16x8 bf = *(const bf16x8*)(wr + nt * 16 * W2S);
                acc2[nt] = __builtin_amdgcn_mfma_f32_16x16x32_bf16(hf, bf, acc2[nt], 0, 0, 0);
            }
        }
        #pragma unroll
        for (int nt = 0; nt < 8; ++nt) {
            #pragma unroll
            for (int r = 0; r < 4; ++r) {
                float o = acc2[nt][r] + b2v[nt];
                float op = __shfl_xor(o, 1, 64);
                if (!(c & 1)) {
                    uint32_t pk = (uint32_t)f2bf(o) | ((uint32_t)f2bf(op) << 16);
                    *(uint32_t*)&hw[(4 * g + r) * HS + nt * 16 + c] = pk;
                }
            }
        }
        if (rowv < E) {
            unsigned short* dst = h2 + (size_t)sl * D;
            #pragma unroll
            for (int j = 0; j < 4; ++j)
                *(uint4*)(dst + (j * 4 + g) * 8) =
                    *(const uint4*)&hw[c * HS + (j * 4 + g) * 8];
        }
    };

    int tile = blockIdx.x * WPB + w;
    if (tile < nT) { loadIdx(tile); loadFrags(); }

    for (; tile < nT; tile += step) {
        f32x4 acc0[8] = {z, z, z, z, z, z, z, z};
        f32x4 acc1[8] = {z, z, z, z, z, z, z, z};
        #pragma unroll
        for (int kk = 0; kk < 9; ++kk) {
            const unsigned short* wr = &w1t[c * W1S + kk * 32 + 8 * g];
            const bf16x8 a0 = pf0[kk], a1 = pf1[kk];
            #pragma unroll
            for (int nt = 0; nt < 8; ++nt) {
                bf16x8 bf = *(const bf16x8*)(wr + nt * 16 * W1S);
                acc0[nt] = __builtin_amdgcn_mfma_f32_16x16x32_bf16(a0, bf, acc0[nt], 0, 0, 0);
                acc1[nt] = __builtin_amdgcn_mfma_f32_16x16x32_bf16(a1, bf, acc1[nt], 0, 0, 0);
            }
        }
        const int sl0 = psl0, sl1 = psl1;
        const int row0 = tile * 32 + c, row1 = tile * 32 + 16 + c;

        const int tn = tile + step;
        loadIdx(tn < nT ? tn : tile);
        loadFrags();                       // gathers hide under the two epilogues

        process(acc0, sl0, row0);
        process(acc1, sl1, row1);
    }
}

// ================= NODE MLP: M=16/wave (small workload) =================
template<bool XBF>
__global__ __launch_bounds__(BLK, 2)
void node_mlp(const float* __restrict__ x, const unsigned short* __restrict__ xbf,
              const float* __restrict__ w1, const float* __restrict__ b1,
              const float* __restrict__ g1, const float* __restrict__ be1,
              const float* __restrict__ w2, const float* __restrict__ b2,
              unsigned short* __restrict__ hnb, int N)
{
    __shared__ unsigned short w1t[128 * W2S];
    __shared__ unsigned short w2t[128 * W2S];
    __shared__ unsigned short hb[WPB][16 * HS];

    const int tid = threadIdx.x;
    for (int i = tid; i < 128 * 128; i += BLK) {
        int k = i >> 7, n = i & 127;
        w1t[n * W2S + k] = f2bf(w1[k * 128 + n]);
        w2t[n * W2S + k] = f2bf(w2[k * 128 + n]);
    }
    __syncthreads();

    const int lane = tid & 63, w = tid >> 6;
    const int g = lane >> 4, c = lane & 15;

    float b1v[8], g1v[8], e1v[8], b2v[8];
    #pragma unroll
    for (int nt = 0; nt < 8; ++nt) {
        b1v[nt] = b1[nt * 16 + c];  g1v[nt] = g1[nt * 16 + c];
        e1v[nt] = be1[nt * 16 + c]; b2v[nt] = b2[nt * 16 + c];
    }

    const int nT = (N + 15) >> 4;
    const f32x4 z = {0.f, 0.f, 0.f, 0.f};
    unsigned short* hw = hb[w];

    for (int tile = blockIdx.x * WPB + w; tile < nT; tile += gridDim.x * WPB) {
        const int row = tile * 16 + c;
        const int rc  = row < N ? row : N - 1;

        f32x4 acc[8] = {z, z, z, z, z, z, z, z};
        #pragma unroll
        for (int kk = 0; kk < 4; ++kk) {
            bf16x8 af;
            if (XBF) af = *(const bf16x8*)(xbf + (size_t)rc * D + kk * 32 + 8 * g);
            else     af = cvt8(x + (size_t)rc * D + kk * 32 + 8 * g);
            const unsigned short* wr = &w1t[c * W2S + kk * 32 + 8 * g];
            #pragma unroll
            for (int nt = 0; nt < 8; ++nt) {
                bf16x8 bf = *(const bf16x8*)(wr + nt * 16 * W2S);
                acc[nt] = __builtin_amdgcn_mfma_f32_16x16x32_bf16(af, bf, acc[nt], 0, 0, 0);
            }
        }

        float mean[4], rstd[4];
        #pragma unroll
        for (int r = 0; r < 4; ++r) {
            float s = 0.f, q = 0.f;
            #pragma unroll
            for (int nt = 0; nt < 8; ++nt) {
                float v = acc[nt][r] + b1v[nt];
                acc[nt][r] = v;
                s += v; q += v * v;
            }
            s += __shfl_xor(s, 1, 64); q += __shfl_xor(q, 1, 64);
            s += __shfl_xor(s, 2, 64); q += __shfl_xor(q, 2, 64);
            s += __shfl_xor(s, 4, 64); q += __shfl_xor(q, 4, 64);
            s += __shfl_xor(s, 8, 64); q += __shfl_xor(q, 8, 64);
            float m = s * (1.f / 128.f);
            mean[r] = m;
            rstd[r] = rsqrtf(q * (1.f / 128.f) - m * m + 1e-5f);
        }
        #pragma unroll
        for (int nt = 0; nt < 8; ++nt) {
            #pragma unroll
            for (int r = 0; r < 4; ++r) {
                float h = fmaxf((acc[nt][r] - mean[r]) * rstd[r] * g1v[nt] + e1v[nt], 0.f);
                float hp = __shfl_xor(h, 1, 64);
                if (!(c & 1)) {
                    uint32_t pk = (uint32_t)f2bf(h) | ((uint32_t)f2bf(hp) << 16);
                    *(uint32_t*)&hw[(4 * g + r) * HS + nt * 16 + c] = pk;
                }
            }
        }
        f32x4 acc2[8] = {z, z, z, z, z, z, z, z};
        #pragma unroll
        for (int kk = 0; kk < 4; ++kk) {
            bf16x8 hf = *(const bf16x8*)&hw[c * HS + kk * 32 + 8 * g];
            const unsigned short* wr = &w2t[c * W2S + kk * 32 + 8 * g];
            #pragma unroll
            for (int nt = 0; nt < 8; ++nt) {
                bf16x8 bf = *(const bf16x8*)(wr + nt * 16 * W2S);
                acc2[nt] = __builtin_amdgcn_mfma_f32_16x16x32_bf16(hf, bf, acc2[nt], 0, 0, 0);
            }
        }
        #pragma unroll
        for (int nt = 0; nt < 8; ++nt) {
            #pragma unroll
            for (int r = 0; r < 4; ++r) {
                float o = acc2[nt][r] + b2v[nt];
                float op = __shfl_xor(o, 1, 64);
                if (!(c & 1)) {
                    uint32_t pk = (uint32_t)f2bf(o) | ((uint32_t)f2bf(op) << 16);
                    *(uint32_t*)&hw[(4 * g + r) * HS + nt * 16 + c] = pk;
                }
            }
        }
        if (row < N) {
            unsigned short* dst = hnb + (size_t)row * D;
            #pragma unroll
            for (int j = 0; j < 4; ++j)
                *(uint4*)(dst + (j * 4 + g) * 8) =
                    *(const uint4*)&hw[c * HS + (j * 4 + g) * 8];
        }
    }
}

// ---- fused aggregate + update (MFMA) ----
template<bool XBF>
__global__ __launch_bounds__(BLK, 2)
void upd3_kernel(const unsigned short* __restrict__ hnb,
                 const unsigned short* __restrict__ h2, const int* __restrict__ starts,
                 const float* __restrict__ x, const unsigned short* __restrict__ xbf,
                 const float* __restrict__ uw, const float* __restrict__ ub,
                 const float* __restrict__ lg, const float* __restrict__ lb,
                 float* __restrict__ out, int N)
{
    __shared__ unsigned short wt[128 * US];
    const int tid = threadIdx.x;
    for (int i = tid; i < 256 * 128; i += BLK) {
        int k = i >> 7, n = i & 127;
        wt[n * US + k] = f2bf(uw[i]);
    }
    __syncthreads();

    const int lane = tid & 63, w = tid >> 6;
    const int g = lane >> 4, c = lane & 15;

    float ubv[8], gv[8], bv[8];
    #pragma unroll
    for (int nt = 0; nt < 8; ++nt) {
        ubv[nt] = ub[nt * 16 + c]; gv[nt] = lg[nt * 16 + c]; bv[nt] = lb[nt * 16 + c];
    }

    const int nT = (N + 15) >> 4;
    for (int tile = blockIdx.x * WPB + w; tile < nT; tile += gridDim.x * WPB) {
        const int row = tile * 16 + c;
        const int rc  = row < N ? row : N - 1;

        const int s = starts[rc], t = starts[rc + 1];
        float ag0[8] = {0,0,0,0,0,0,0,0}, ag1[8] = {0,0,0,0,0,0,0,0};
        float ag2[8] = {0,0,0,0,0,0,0,0}, ag3[8] = {0,0,0,0,0,0,0,0};
        for (int j = s; j < t; ++j) {
            const unsigned short* pr = h2 + (size_t)j * D + 8 * g;
            uint4 v0 = *(const uint4*)(pr);
            uint4 v1 = *(const uint4*)(pr + 32);
            uint4 v2 = *(const uint4*)(pr + 64);
            uint4 v3 = *(const uint4*)(pr + 96);
            ag0[0] += bflo(v0.x); ag0[1] += bfhi(v0.x); ag0[2] += bflo(v0.y); ag0[3] += bfhi(v0.y);
            ag0[4] += bflo(v0.z); ag0[5] += bfhi(v0.z); ag0[6] += bflo(v0.w); ag0[7] += bfhi(v0.w);
            ag1[0] += bflo(v1.x); ag1[1] += bfhi(v1.x); ag1[2] += bflo(v1.y); ag1[3] += bfhi(v1.y);
            ag1[4] += bflo(v1.z); ag1[5] += bfhi(v1.z); ag1[6] += bflo(v1.w); ag1[7] += bfhi(v1.w);
            ag2[0] += bflo(v2.x); ag2[1] += bfhi(v2.x); ag2[2] += bflo(v2.y); ag2[3] += bfhi(v2.y);
            ag2[4] += bflo(v2.z); ag2[5] += bfhi(v2.z); ag2[6] += bflo(v2.w); ag2[7] += bfhi(v2.w);
            ag3[0] += bflo(v3.x); ag3[1] += bfhi(v3.x); ag3[2] += bflo(v3.y); ag3[3] += bfhi(v3.y);
            ag3[4] += bflo(v3.z); ag3[5] += bfhi(v3.z); ag3[6] += bflo(v3.w); ag3[7] += bfhi(v3.w);
        }

        const f32x4 z = {0.f, 0.f, 0.f, 0.f};
        f32x4 acc[8] = {z, z, z, z, z, z, z, z};
        #pragma unroll
        for (int kk = 0; kk < 8; ++kk) {
            bf16x8 af;
            if (kk < 4) {
                af = *(const bf16x8*)(hnb + (size_t)rc * D + kk * 32 + 8 * g);
            } else {
                const float* agp = (kk == 4) ? ag0 : (kk == 5) ? ag1 : (kk == 6) ? ag2 : ag3;
                #pragma unroll
                for (int i = 0; i < 8; ++i) af[i] = (short)f2bf(agp[i]);
            }
            const unsigned short* wr = &wt[c * US + kk * 32 + 8 * g];
            #pragma unroll
            for (int nt = 0; nt < 8; ++nt) {
                bf16x8 bf = *(const bf16x8*)(wr + nt * 16 * US);
                acc[nt] = __builtin_amdgcn_mfma_f32_16x16x32_bf16(af, bf, acc[nt], 0, 0, 0);
            }
        }

        float mean[4], rstd[4];
        #pragma unroll
        for (int r = 0; r < 4; ++r) {
            const int row4 = tile * 16 + 4 * g + r;
            const int r4c = row4 < N ? row4 : N - 1;
            float s2 = 0.f, q = 0.f;
            #pragma unroll
            for (int nt = 0; nt < 8; ++nt) {
                float xr;
                if (XBF) xr = bflo((uint32_t)xbf[(size_t)r4c * D + nt * 16 + c]);
                else     xr = x[(size_t)r4c * D + nt * 16 + c];
                float v = acc[nt][r] + ubv[nt] + xr;
                acc[nt][r] = v;
                s2 += v; q += v * v;
            }
            s2 += __shfl_xor(s2, 1, 64); q += __shfl_xor(q, 1, 64);
            s2 += __shfl_xor(s2, 2, 64); q += __shfl_xor(q, 2, 64);
            s2 += __shfl_xor(s2, 4, 64); q += __shfl_xor(q, 4, 64);
            s2 += __shfl_xor(s2, 8, 64); q += __shfl_xor(q, 8, 64);
            float m = s2 * (1.f / 128.f);
            mean[r] = m;
            rstd[r] = rsqrtf(q * (1.f / 128.f) - m * m + 1e-5f);
        }
        #pragma unroll
        for (int r = 0; r < 4; ++r) {
            const int row4 = tile * 16 + 4 * g + r;
            if (row4 < N) {
                #pragma unroll
                for (int nt = 0; nt < 8; ++nt)
                    out[(size_t)row4 * D + nt * 16 + c] =
                        (acc[nt][r] - mean[r]) * rstd[r] * gv[nt] + bv[nt];
            }
        }
    }
}

extern "C" void kernel_launch(void* const* d_in, const int* in_sizes, int n_in,
                              void* d_out, int out_size, void* d_ws, size_t ws_size,
                              hipStream_t stream)
{
    const float* x    = (const float*)d_in[0];
    const float* ea   = (const float*)d_in[1];
    const float* nw1  = (const float*)d_in[3];
    const float* nb1  = (const float*)d_in[4];
    const float* ng1  = (const float*)d_in[5];
    const float* nbe1 = (const float*)d_in[6];
    const float* nw2  = (const float*)d_in[7];
    const float* nb2  = (const float*)d_in[8];
    const float* ew1  = (const float*)d_in[9];
    const float* eb1  = (const float*)d_in[10];
    const float* eg1  = (const float*)d_in[11];
    const float* ebe1 = (const float*)d_in[12];
    const float* ew2  = (const float*)d_in[13];
    const float* eb2  = (const float*)d_in[14];
    const float* uw   = (const float*)d_in[15];
    const float* ub   = (const float*)d_in[16];
    const float* lg   = (const float*)d_in[17];
    const float* lb   = (const float*)d_in[18];
    const int*   eidx = (const int*)d_in[19];

    const int N = in_sizes[0] / D;
    const int E = in_sizes[1] / ED;

    char* base = (char*)d_ws;
    size_t off = 0;
    auto alloc = [&](size_t bytes) -> char* {
        char* p = base + off;
        off = (off + bytes + 255) & ~(size_t)255;
        return p;
    };

    unsigned short* hnb  = (unsigned short*)alloc((size_t)N * D * 2);
    unsigned short* xbf  = (unsigned short*)alloc((size_t)N * D * 2);
    int* cnt    = (int*)alloc((size_t)N * 4);
    int* starts = (int*)alloc(((size_t)N + 1) * 4);
    int* cursor = (int*)alloc((size_t)N * 4);
    int* bsum   = (int*)alloc(1024 * 4);
    int* slotA  = (int*)alloc((size_t)E * 4);
    unsigned short* h2 = (unsigned short*)alloc((size_t)E * D * 2);
    const size_t needA = off;

    const int n8 = N * D / 8;
    const int egrid = (E + 511) / 512;
    const int nb = (N + 1023) / 1024;
    const int ugrid = (((N + 15) / 16) + WPB - 1) / WPB;

    if (ws_size >= needA && nb <= 1024) {
        hipMemsetAsync(cnt, 0, (size_t)N * 4, stream);
        cvt_count_kernel<<<(n8 + E + 511) / 512, 512, 0, stream>>>(
            x, xbf, n8, eidx, cnt, E);
        scan_blk_kernel<<<nb, 1024, 0, stream>>>(cnt, cursor, bsum, N);
        scan_top_kernel<<<1, 1024, 0, stream>>>(bsum, nb);
        scan_add_kernel<<<nb, 1024, 0, stream>>>(cursor, bsum, starts, cursor, N, E);
        fill_kernel<<<egrid, 512, 0, stream>>>(eidx, cursor, slotA, E);
        node_mlp<true><<<GRID, BLK, 0, stream>>>(
            x, xbf, nw1, nb1, ng1, nbe1, nw2, nb2, hnb, N);
        edge_mlp<true><<<GRID, BLK, 0, stream>>>(
            x, xbf, ea, eidx, slotA, ew1, eb1, eg1, ebe1, ew2, eb2, h2, E);
        upd3_kernel<true><<<ugrid, BLK, 0, stream>>>(
            hnb, h2, starts, x, xbf, uw, ub, lg, lb, (float*)d_out, N);
        return;
    }

    // Fallback (no xbf precompute): same pipeline, cvt-on-load
    off = 0;
    unsigned short* hnb2 = (unsigned short*)alloc((size_t)N * D * 2);
    int* cnt2    = (int*)alloc((size_t)N * 4);
    int* starts2 = (int*)alloc(((size_t)N + 1) * 4);
    int* cursor2 = (int*)alloc((size_t)N * 4);
    int* bsum2   = (int*)alloc(1024 * 4);
    int* slotB   = (int*)alloc((size_t)E * 4);
    unsigned short* h2b = (unsigned short*)alloc((size_t)E * D * 2);

    hipMemsetAsync(cnt2, 0, (size_t)N * 4, stream);
    cvt_count_kernel<<<(E + 511) / 512, 512, 0, stream>>>(
        x, nullptr, 0, eidx, cnt2, E);
    scan_blk_kernel<<<nb, 1024, 0, stream>>>(cnt2, cursor2, bsum2, N);
    scan_top_kernel<<<1, 1024, 0, stream>>>(bsum2, nb);
    scan_add_kernel<<<nb, 1024, 0, stream>>>(cursor2, bsum2, starts2, cursor2, N, E);
    fill_kernel<<<egrid, 512, 0, stream>>>(eidx, cursor2, slotB, E);
    node_mlp<false><<<GRID, BLK, 0, stream>>>(
        x, nullptr, nw1, nb1, ng1, nbe1, nw2, nb2, hnb2, N);
    edge_mlp<false><<<GRID, BLK, 0, stream>>>(
        x, nullptr, ea, eidx, slotB, ew1, eb1, eg1, ebe1, ew2, eb2, h2b, E);
    upd3_kernel<false><<<ugrid, BLK, 0, stream>>>(
        hnb2, h2b, starts2, x, nullptr, uw, ub, lg, lb, (float*)d_out, N);
}